// Round 3
// baseline (784.890 us; speedup 1.0000x reference)
//
#include <hip/hip_runtime.h>
#include <hip/hip_bf16.h>

typedef unsigned int u32;
typedef unsigned char u8;

#define B_ 256
#define T_ 512
#define E_ 100
#define H_ 64
#define K_ 17
#define V_ 8000

// ---- ws layout (bytes) ----
#define WS_G     0            // 2 * 8000 * 256 * 4 = 16,384,000
#define WS_H     16384000     // 2 * 256 * 512 * 64 * 4 = 67,108,864
#define WS_EMIT  83492864     // 131072 * 17 * 4 = 8,912,896
#define WS_BP    92405760     // 256 * 512 * 32 = 4,194,304
#define WS_LAST  96600064     // 256 * 4

// ============ K1: G[v][u*4+g] = emb[v] @ Wih[g*64+u].T + bih + bhh ============
__global__ __launch_bounds__(256) void k1_build_G(
    const float* __restrict__ emb,
    const float* __restrict__ Wih_f,
    const float* __restrict__ bih_f,
    const float* __restrict__ bhh_f,
    const float* __restrict__ Wih_b,
    const float* __restrict__ bih_b,
    const float* __restrict__ bhh_b,
    float* __restrict__ G)
{
  __shared__ float xl[32 * E_];
  int v0 = blockIdx.x * 32;
  int dir = blockIdx.y;
  int tid = threadIdx.x;
  const float* Wih = dir ? Wih_b : Wih_f;
  const float* bih = dir ? bih_b : bih_f;
  const float* bhh = dir ? bhh_b : bhh_f;

  for (int i = tid; i < 32 * E_; i += 256) xl[i] = emb[v0 * E_ + i];

  int u = tid >> 2, g = tid & 3;
  int row = (g << 6) + u;
  float4 A4[25];
  {
    const float4* wp = reinterpret_cast<const float4*>(Wih + row * E_); // 400B rows, 16B aligned
#pragma unroll
    for (int q = 0; q < 25; ++q) A4[q] = wp[q];
  }
  float bias = __fadd_rn(bih[row], bhh[row]);
  __syncthreads();

  float* Gd = G + (size_t)dir * V_ * 256;
  for (int vi = 0; vi < 32; ++vi) {
    const float* xp = &xl[vi * E_];   // vi*400B, 16B aligned
    float a0 = bias, a1 = 0.f, a2 = 0.f, a3 = 0.f;
#pragma unroll
    for (int q = 0; q < 25; ++q) {
      float4 w4 = A4[q];
      float4 x4 = *reinterpret_cast<const float4*>(&xp[4 * q]);
      a0 = fmaf(w4.x, x4.x, a0);
      a1 = fmaf(w4.y, x4.y, a1);
      a2 = fmaf(w4.z, x4.z, a2);
      a3 = fmaf(w4.w, x4.w, a3);
    }
    Gd[(v0 + vi) * 256 + tid] = (a0 + a1) + (a2 + a3);
  }
}

// ============ K2: BiLSTM recurrence. 1 block = (b, dir), 4 waves ============
// lane l of wave w: unit u = 16w + (l>>2), gate g = l&3 (0=i,1=f,2=g,3=o)
__global__ __launch_bounds__(256) void k2_lstm(
    const int* __restrict__ data,
    const float* __restrict__ G,
    const float* __restrict__ Whh_f,
    const float* __restrict__ Whh_b,
    float* __restrict__ hout)
{
  __shared__ __align__(16) float hls[2][64];
  int bid = blockIdx.x;
  int b = bid & 255;
  int dir = bid >> 8;
  int tid = threadIdx.x;
  int w = tid >> 6, l = tid & 63;
  int u = (w << 4) + (l >> 2);
  int g = l & 3;
  int row = (g << 6) + u;
  const float* Whh = dir ? Whh_b : Whh_f;

  float W[64];
  {
    const float4* wp = reinterpret_cast<const float4*>(Whh + row * 64); // 256B rows
#pragma unroll
    for (int q = 0; q < 16; ++q) {
      float4 v = wp[q];
      W[q * 4 + 0] = v.x;
      W[q * 4 + 1] = v.y;
      W[q * 4 + 2] = v.z;
      W[q * 4 + 3] = v.w;
    }
  }
  if (tid < 64) hls[0][tid] = 0.0f;
  float c = 0.0f;
  const int* tokp = data + b * T_;
  const float* Gd = G + (size_t)dir * V_ * 256;
  float* hob = hout + ((size_t)(dir * B_ + b)) * T_ * H_;

  int tt0 = dir ? (T_ - 1) : 0;
  int tt1 = dir ? (T_ - 2) : 1;
  float g0 = Gd[(size_t)tokp[tt0] * 256 + tid];
  float g1 = Gd[(size_t)tokp[tt1] * 256 + tid];
  __syncthreads();

  int cur = 0;
  for (int s = 0; s < T_; ++s) {
    int tt = dir ? (T_ - 1 - s) : s;
    float g2 = 0.0f;
    if (s < T_ - 2) {
      int ttn = dir ? (T_ - 3 - s) : (s + 2);
      g2 = Gd[(size_t)tokp[ttn] * 256 + tid];
    }
    // gate = G[tok] + Whh[row] . h_prev   (4 partial chains for ILP)
    const float* hb_ = hls[cur];
    float a0 = g0, a1 = 0.f, a2 = 0.f, a3 = 0.f;
#pragma unroll
    for (int k4 = 0; k4 < 16; ++k4) {
      float4 h4 = *reinterpret_cast<const float4*>(&hb_[k4 * 4]);
      a0 = fmaf(W[k4 * 4 + 0], h4.x, a0);
      a1 = fmaf(W[k4 * 4 + 1], h4.y, a1);
      a2 = fmaf(W[k4 * 4 + 2], h4.z, a2);
      a3 = fmaf(W[k4 * 4 + 3], h4.w, a3);
    }
    float acc = ((a0 + a1) + a2) + a3;
    float act;
    if (g == 2) act = tanhf(acc);
    else        act = 1.0f / (1.0f + expf(-acc));
    int base = l & ~3;
    float iv = __shfl(act, base + 0, 64);
    float fv = __shfl(act, base + 1, 64);
    float gv = __shfl(act, base + 2, 64);
    float ov = __shfl(act, base + 3, 64);
    // c = sig(f)*c + sig(i)*tanh(g)  (np rounding order: two muls then add)
    c = __fadd_rn(__fmul_rn(fv, c), __fmul_rn(iv, gv));
    float hn = __fmul_rn(ov, tanhf(c));
    if (g == 0) {
      hls[cur ^ 1][u] = hn;
      hob[tt * H_ + u] = hn;
    }
    __syncthreads();
    cur ^= 1;
    g0 = g1; g1 = g2;
  }
}

// ============ K3: emissions = [hf|hb] @ W_out.T + b_out ============
__global__ __launch_bounds__(256) void k3_emit(
    const float* __restrict__ hbuf,
    const float* __restrict__ W_out,
    const float* __restrict__ b_out,
    float* __restrict__ emit)
{
  __shared__ float hl[64][132];
  __shared__ float Wl[17][132];
  int tid = threadIdx.x;
  int p0 = blockIdx.x * 64;  // flat position base (b*T + t), 64 consecutive t
  const float* hf = hbuf;
  const float* hb = hbuf + (size_t)B_ * T_ * H_;
#pragma unroll
  for (int i = 0; i < 4; ++i) {
    int idx = tid + i * 256;       // float4 index among 1024
    int pos = idx >> 4, e4 = idx & 15;
    float4 v = reinterpret_cast<const float4*>(hf + (size_t)p0 * 64)[idx];
    *reinterpret_cast<float4*>(&hl[pos][e4 * 4]) = v;
    float4 v2 = reinterpret_cast<const float4*>(hb + (size_t)p0 * 64)[idx];
    *reinterpret_cast<float4*>(&hl[pos][64 + e4 * 4]) = v2;
  }
  for (int i = tid; i < 17 * 128; i += 256) {
    int k = i >> 7, e = i & 127;
    Wl[k][e] = W_out[i];
  }
  __syncthreads();

  int pos = tid >> 2, ks = tid & 3;
  float acc[5] = {0.f, 0.f, 0.f, 0.f, 0.f};
#pragma unroll
  for (int e4 = 0; e4 < 32; ++e4) {
    float4 x4 = *reinterpret_cast<const float4*>(&hl[pos][e4 * 4]);
#pragma unroll
    for (int kk = 0; kk < 5; ++kk) {
      int k = ks + kk * 4;
      if (k < K_) {
        float4 w4 = *reinterpret_cast<const float4*>(&Wl[k][e4 * 4]);
        acc[kk] = fmaf(x4.x, w4.x, acc[kk]);
        acc[kk] = fmaf(x4.y, w4.y, acc[kk]);
        acc[kk] = fmaf(x4.z, w4.z, acc[kk]);
        acc[kk] = fmaf(x4.w, w4.w, acc[kk]);
      }
    }
  }
#pragma unroll
  for (int kk = 0; kk < 5; ++kk) {
    int k = ks + kk * 4;
    if (k < K_)
      emit[(size_t)(p0 + pos) * K_ + k] = __fadd_rn(acc[kk], b_out[k]);
  }
}

// ============ K4: Viterbi forward. 1 wave per b; lane = (half ic, tag j) ============
__global__ __launch_bounds__(64) void k4_viterbi(
    const float* __restrict__ emit,
    const float* __restrict__ trans,
    const float* __restrict__ start_trans,
    const float* __restrict__ end_trans,
    u8* __restrict__ bp,
    int* __restrict__ last,
    float* __restrict__ out)
{
  int b = blockIdx.x;
  int l = threadIdx.x;
  int ic = l >> 5;
  int j = l & 31;
  int jc = (j < K_) ? j : 0;
  int i0 = ic ? 9 : 0;
  int cnt = ic ? 8 : 9;
  float tr[9];
#pragma unroll
  for (int r = 0; r < 9; ++r) {
    int i = i0 + r;
    tr[r] = (r < cnt) ? trans[i * K_ + jc] : -__builtin_inff();
  }
  const float* eb = emit + (size_t)b * T_ * K_;
  float endt = end_trans[jc];
  float s = __fadd_rn(start_trans[jc], eb[jc]);
  u8* bpb = bp + (size_t)b * T_ * 32;
  float epre = eb[K_ + jc];

  for (int t = 1; t < T_; ++t) {
    float ej = epre;
    if (t + 1 < T_) epre = eb[(size_t)(t + 1) * K_ + jc];
    float sv[9];
#pragma unroll
    for (int r = 0; r < 9; ++r) sv[r] = __shfl(s, (l & 32) + i0 + r, 64);
    // np rounding order: cand = (score_i + trans_ij) + emit_j, then max/argmax
    float m = __fadd_rn(__fadd_rn(sv[0], tr[0]), ej);
    int idx = i0;
#pragma unroll
    for (int r = 1; r < 9; ++r) {
      float cand = __fadd_rn(__fadd_rn(sv[r], tr[r]), ej);
      if (cand > m) { m = cand; idx = i0 + r; }   // strict >: first-index ties
    }
    float m2 = __shfl_xor(m, 32, 64);
    int idx2 = __shfl_xor(idx, 32, 64);
    bool take = (m2 > m) || ((m2 == m) && (idx2 < idx));
    if (take) { m = m2; idx = idx2; }
    s = m;
    if (ic == 0 && j < K_) bpb[(size_t)(t - 1) * 32 + j] = (u8)idx;
  }
  float fin = __fadd_rn(s, endt);
  float bm = __shfl(fin, (l & 32), 64);
  int bi = 0;
#pragma unroll
  for (int jj = 1; jj < K_; ++jj) {
    float v = __shfl(fin, (l & 32) + jj, 64);
    if (v > bm) { bm = v; bi = jj; }
  }
  if (l == 0) {
    out[b] = bm;
    last[b] = bi;
    out[256 + (size_t)b * T_ + (T_ - 1)] = (float)bi;
  }
}

// ============ K5: backtrace ============
__global__ __launch_bounds__(64) void k5_backtrace(
    const u8* __restrict__ bp,
    const int* __restrict__ last,
    float* __restrict__ out)
{
  int b = blockIdx.x * 64 + threadIdx.x;
  const uint4* bpp = reinterpret_cast<const uint4*>(bp + (size_t)b * T_ * 32);
  int tag = last[b];
  uint4 A = bpp[510 * 2];
  uint4 Bv = bpp[510 * 2 + 1];
  for (int t = 510; t >= 0; --t) {
    uint4 A2 = A, B2 = Bv;
    if (t > 0) { A2 = bpp[(t - 1) * 2]; B2 = bpp[(t - 1) * 2 + 1]; }
    u32 dw = (tag < 8) ? ((tag < 4) ? A.x : A.y) : ((tag < 12) ? A.z : A.w);
    dw = (tag < 16) ? dw : Bv.x;
    tag = (int)((dw >> ((tag & 3) * 8)) & 0xffu);
    out[256 + (size_t)b * T_ + t] = (float)tag;
    A = A2; Bv = B2;
  }
}

extern "C" void kernel_launch(void* const* d_in, const int* in_sizes, int n_in,
                              void* d_out, int out_size, void* d_ws, size_t ws_size,
                              hipStream_t stream) {
  const int*   data  = (const int*)d_in[0];
  const float* emb   = (const float*)d_in[2];
  const float* Wih_f = (const float*)d_in[3];
  const float* Whh_f = (const float*)d_in[4];
  const float* bih_f = (const float*)d_in[5];
  const float* bhh_f = (const float*)d_in[6];
  const float* Wih_b = (const float*)d_in[7];
  const float* Whh_b = (const float*)d_in[8];
  const float* bih_b = (const float*)d_in[9];
  const float* bhh_b = (const float*)d_in[10];
  const float* W_out = (const float*)d_in[11];
  const float* b_out = (const float*)d_in[12];
  const float* trans = (const float*)d_in[13];
  const float* start_trans = (const float*)d_in[14];
  const float* end_trans   = (const float*)d_in[15];

  char* ws = (char*)d_ws;
  float* G    = (float*)(ws + WS_G);
  float* hbuf = (float*)(ws + WS_H);
  float* emit = (float*)(ws + WS_EMIT);
  u8*    bp   = (u8*)(ws + WS_BP);
  int*   lastp = (int*)(ws + WS_LAST);
  float* out = (float*)d_out;

  k1_build_G<<<dim3(250, 2), 256, 0, stream>>>(emb, Wih_f, bih_f, bhh_f,
                                               Wih_b, bih_b, bhh_b, G);
  k2_lstm<<<512, 256, 0, stream>>>(data, G, Whh_f, Whh_b, hbuf);
  k3_emit<<<2048, 256, 0, stream>>>(hbuf, W_out, b_out, emit);
  k4_viterbi<<<256, 64, 0, stream>>>(emit, trans, start_trans, end_trans,
                                     bp, lastp, out);
  k5_backtrace<<<4, 64, 0, stream>>>(bp, lastp, out);
}

// Round 4
// 716.462 us; speedup vs baseline: 1.0955x; 1.0955x over previous
//
#include <hip/hip_runtime.h>
#include <hip/hip_bf16.h>

typedef unsigned int u32;
typedef unsigned char u8;

#define B_ 256
#define T_ 512
#define E_ 100
#define H_ 64
#define K_ 17
#define V_ 8000

// ---- ws layout (bytes) ----
#define WS_G     0            // 2 * 8000 * 256 * 4 = 16,384,000
#define WS_H     16384000     // 2 * 256 * 512 * 64 * 4 = 67,108,864
#define WS_EMIT  83492864     // 131072 * 17 * 4 = 8,912,896
#define WS_BP    92405760     // 256 * 512 * 32 = 4,194,304
#define WS_LAST  96600064     // 256 * 4

// ============ K1: G[v][u*4+g] = emb[v] @ Wih[g*64+u].T + bih + bhh ============
__global__ __launch_bounds__(256) void k1_build_G(
    const float* __restrict__ emb,
    const float* __restrict__ Wih_f,
    const float* __restrict__ bih_f,
    const float* __restrict__ bhh_f,
    const float* __restrict__ Wih_b,
    const float* __restrict__ bih_b,
    const float* __restrict__ bhh_b,
    float* __restrict__ G)
{
  __shared__ float xl[32 * E_];
  int v0 = blockIdx.x * 32;
  int dir = blockIdx.y;
  int tid = threadIdx.x;
  const float* Wih = dir ? Wih_b : Wih_f;
  const float* bih = dir ? bih_b : bih_f;
  const float* bhh = dir ? bhh_b : bhh_f;

  for (int i = tid; i < 32 * E_; i += 256) xl[i] = emb[v0 * E_ + i];

  int u = tid >> 2, g = tid & 3;
  int row = (g << 6) + u;
  float4 A4[25];
  {
    const float4* wp = reinterpret_cast<const float4*>(Wih + row * E_); // 400B rows, 16B aligned
#pragma unroll
    for (int q = 0; q < 25; ++q) A4[q] = wp[q];
  }
  float bias = __fadd_rn(bih[row], bhh[row]);
  __syncthreads();

  float* Gd = G + (size_t)dir * V_ * 256;
  for (int vi = 0; vi < 32; ++vi) {
    const float* xp = &xl[vi * E_];   // vi*400B, 16B aligned
    float a0 = bias, a1 = 0.f, a2 = 0.f, a3 = 0.f;
#pragma unroll
    for (int q = 0; q < 25; ++q) {
      float4 w4 = A4[q];
      float4 x4 = *reinterpret_cast<const float4*>(&xp[4 * q]);
      a0 = fmaf(w4.x, x4.x, a0);
      a1 = fmaf(w4.y, x4.y, a1);
      a2 = fmaf(w4.z, x4.z, a2);
      a3 = fmaf(w4.w, x4.w, a3);
    }
    Gd[(v0 + vi) * 256 + tid] = (a0 + a1) + (a2 + a3);
  }
}

// ============ K2: BiLSTM recurrence. 1 block = (b, dir), 8 waves / 512 thr ============
// lane: u_local = l>>3, r = l&7, g = r>>1, half = r&1; unit u = w*8 + u_local.
// Each (u,g) gate computed by 2 lanes (32-FMA halves), combined via shfl_xor(1).
__global__ __launch_bounds__(512, 4) void k2_lstm(
    const int* __restrict__ data,
    const float* __restrict__ G,
    const float* __restrict__ Whh_f,
    const float* __restrict__ Whh_b,
    float* __restrict__ hout)
{
  __shared__ __align__(16) float hls[2][64];
  int bid = blockIdx.x;
  int b = bid & 255;
  int dir = bid >> 8;
  int tid = threadIdx.x;
  int w = tid >> 6, l = tid & 63;
  int ul = l >> 3;
  int r = l & 7;
  int g = r >> 1;
  int half = r & 1;
  int u = (w << 3) + ul;
  int row = (g << 6) + u;
  int gidx = (u << 2) + g;
  const float* Whh = dir ? Whh_b : Whh_f;

  float W[32];
  {
    const float4* wp = reinterpret_cast<const float4*>(Whh + row * 64 + half * 32);
#pragma unroll
    for (int q = 0; q < 8; ++q) {
      float4 v = wp[q];
      W[q * 4 + 0] = v.x;
      W[q * 4 + 1] = v.y;
      W[q * 4 + 2] = v.z;
      W[q * 4 + 3] = v.w;
    }
  }
  // branchless activation constants:
  // sigmoid(x) = rcp(1 + exp2(-x*log2e)); tanh(x) = 2*rcp(1+exp2(-2x*log2e)) - 1
  const float L2E = 1.4426950408889634f;
  float zs = (g == 2) ? (-2.0f * L2E) : (-L2E);
  float ma = (g == 2) ? 2.0f : 1.0f;
  float aa = (g == 2) ? -1.0f : 0.0f;

  if (tid < 64) hls[0][tid] = 0.0f;
  float c = 0.0f;
  const int* tokp = data + b * T_;
  const float* Gd = G + (size_t)dir * V_ * 256;
  float* hob = hout + ((size_t)(dir * B_ + b)) * T_ * H_;

  float g0 = Gd[(size_t)tokp[dir ? (T_ - 1) : 0] * 256 + gidx];
  float g1 = Gd[(size_t)tokp[dir ? (T_ - 2) : 1] * 256 + gidx];
  __syncthreads();

  int cur = 0;
  for (int s = 0; s < T_; ++s) {
    int tt = dir ? (T_ - 1 - s) : s;
    float g2 = 0.0f;
    if (s < T_ - 2) {
      int ttn = dir ? (T_ - 3 - s) : (s + 2);
      g2 = Gd[(size_t)tokp[ttn] * 256 + gidx];
    }
    const float* hb_ = hls[cur] + (half << 5);
    float a0 = (half == 0) ? g0 : 0.0f;
    float a1 = 0.f, a2 = 0.f, a3 = 0.f;
#pragma unroll
    for (int k4 = 0; k4 < 8; ++k4) {
      float4 h4 = *reinterpret_cast<const float4*>(&hb_[k4 * 4]);
      a0 = fmaf(W[k4 * 4 + 0], h4.x, a0);
      a1 = fmaf(W[k4 * 4 + 1], h4.y, a1);
      a2 = fmaf(W[k4 * 4 + 2], h4.z, a2);
      a3 = fmaf(W[k4 * 4 + 3], h4.w, a3);
    }
    float part = (a0 + a1) + (a2 + a3);
    float full = part + __shfl_xor(part, 1, 64);   // combine the two 32-halves
    float ex = __builtin_amdgcn_exp2f(full * zs);
    float sg = __builtin_amdgcn_rcpf(1.0f + ex);
    float act = fmaf(ma, sg, aa);
    int base = l & 56;
    float iv = __shfl(act, base + 0, 64);
    float fv = __shfl(act, base + 2, 64);
    float gv = __shfl(act, base + 4, 64);
    float ov = __shfl(act, base + 6, 64);
    // c = sig(f)*c + sig(i)*tanh(g)  (np rounding order: two muls then add)
    c = __fadd_rn(__fmul_rn(fv, c), __fmul_rn(iv, gv));
    float tc = fmaf(2.0f,
                    __builtin_amdgcn_rcpf(1.0f + __builtin_amdgcn_exp2f(c * (-2.0f * L2E))),
                    -1.0f);
    float hn = __fmul_rn(ov, tc);
    if (r == 0) {
      hls[cur ^ 1][u] = hn;
      hob[tt * H_ + u] = hn;
    }
    __syncthreads();
    cur ^= 1;
    g0 = g1; g1 = g2;
  }
}

// ============ K3: emissions = [hf|hb] @ W_out.T + b_out ============
__global__ __launch_bounds__(256) void k3_emit(
    const float* __restrict__ hbuf,
    const float* __restrict__ W_out,
    const float* __restrict__ b_out,
    float* __restrict__ emit)
{
  __shared__ float hl[64][132];
  __shared__ float Wl[17][132];
  int tid = threadIdx.x;
  int p0 = blockIdx.x * 64;  // flat position base (b*T + t), 64 consecutive t
  const float* hf = hbuf;
  const float* hb = hbuf + (size_t)B_ * T_ * H_;
#pragma unroll
  for (int i = 0; i < 4; ++i) {
    int idx = tid + i * 256;       // float4 index among 1024
    int pos = idx >> 4, e4 = idx & 15;
    float4 v = reinterpret_cast<const float4*>(hf + (size_t)p0 * 64)[idx];
    *reinterpret_cast<float4*>(&hl[pos][e4 * 4]) = v;
    float4 v2 = reinterpret_cast<const float4*>(hb + (size_t)p0 * 64)[idx];
    *reinterpret_cast<float4*>(&hl[pos][64 + e4 * 4]) = v2;
  }
  for (int i = tid; i < 17 * 128; i += 256) {
    int k = i >> 7, e = i & 127;
    Wl[k][e] = W_out[i];
  }
  __syncthreads();

  int pos = tid >> 2, ks = tid & 3;
  float acc[5] = {0.f, 0.f, 0.f, 0.f, 0.f};
#pragma unroll
  for (int e4 = 0; e4 < 32; ++e4) {
    float4 x4 = *reinterpret_cast<const float4*>(&hl[pos][e4 * 4]);
#pragma unroll
    for (int kk = 0; kk < 5; ++kk) {
      int k = ks + kk * 4;
      if (k < K_) {
        float4 w4 = *reinterpret_cast<const float4*>(&Wl[k][e4 * 4]);
        acc[kk] = fmaf(x4.x, w4.x, acc[kk]);
        acc[kk] = fmaf(x4.y, w4.y, acc[kk]);
        acc[kk] = fmaf(x4.z, w4.z, acc[kk]);
        acc[kk] = fmaf(x4.w, w4.w, acc[kk]);
      }
    }
  }
#pragma unroll
  for (int kk = 0; kk < 5; ++kk) {
    int k = ks + kk * 4;
    if (k < K_)
      emit[(size_t)(p0 + pos) * K_ + k] = __fadd_rn(acc[kk], b_out[k]);
  }
}

// ============ K4: Viterbi forward. 1 wave per b; lane = (half ic, tag j) ============
#define AMAX(vA, iA, vB, iB) { bool tk_ = (vB) > (vA); if (tk_) { vA = (vB); iA = (iB); } }

__global__ __launch_bounds__(64) void k4_viterbi(
    const float* __restrict__ emit,
    const float* __restrict__ trans,
    const float* __restrict__ start_trans,
    const float* __restrict__ end_trans,
    u8* __restrict__ bp,
    int* __restrict__ last,
    float* __restrict__ out)
{
  int b = blockIdx.x;
  int l = threadIdx.x;
  int ic = l >> 5;
  int hbase = l & 32;
  int j = l & 31;
  int jc = (j < K_) ? j : 0;
  int i0 = ic ? 9 : 0;
  int cnt = ic ? 8 : 9;
  float tr[9];
#pragma unroll
  for (int q = 0; q < 9; ++q)
    tr[q] = (q < cnt) ? trans[(i0 + q) * K_ + jc] : -__builtin_inff();
  const float* eb = emit + (size_t)b * T_ * K_;
  float endt = end_trans[jc];
  float s = __fadd_rn(start_trans[jc], eb[jc]);
  u8* bpb = bp + (size_t)b * T_ * 32;
  float e0 = eb[K_ + jc];
  float e1 = eb[2 * K_ + jc];

  for (int t = 1; t < T_; ++t) {
    float ej = e0;
    e0 = e1;
    if (t + 2 < T_) e1 = eb[(size_t)(t + 2) * K_ + jc];
    float sv[9];
#pragma unroll
    for (int q = 0; q < 9; ++q) sv[q] = __shfl(s, hbase + i0 + q, 64);
    // np rounding order: cand = (score_i + trans_ij) + emit_j
    float cd[9];
#pragma unroll
    for (int q = 0; q < 9; ++q) cd[q] = __fadd_rn(__fadd_rn(sv[q], tr[q]), ej);
    // tree argmax; strict > with left-priority == np first-index tie rule
    float v01 = cd[0]; int x01 = i0;     AMAX(v01, x01, cd[1], i0 + 1);
    float v23 = cd[2]; int x23 = i0 + 2; AMAX(v23, x23, cd[3], i0 + 3);
    float v45 = cd[4]; int x45 = i0 + 4; AMAX(v45, x45, cd[5], i0 + 5);
    float v67 = cd[6]; int x67 = i0 + 6; AMAX(v67, x67, cd[7], i0 + 7);
    AMAX(v01, x01, v23, x23);
    AMAX(v45, x45, v67, x67);
    AMAX(v01, x01, v45, x45);
    AMAX(v01, x01, cd[8], i0 + 8);
    float m = v01; int idx = x01;
    float m2 = __shfl_xor(m, 32, 64);
    int idx2 = __shfl_xor(idx, 32, 64);
    bool take = (m2 > m) || ((m2 == m) && (idx2 < idx));
    if (take) { m = m2; idx = idx2; }
    s = m;
    if (ic == 0 && j < K_) bpb[(size_t)(t - 1) * 32 + j] = (u8)idx;
  }
  float fin = __fadd_rn(s, endt);
  float bm = __shfl(fin, hbase, 64);
  int bi = 0;
#pragma unroll
  for (int jj = 1; jj < K_; ++jj) {
    float v = __shfl(fin, hbase + jj, 64);
    if (v > bm) { bm = v; bi = jj; }
  }
  if (l == 0) {
    out[b] = bm;
    last[b] = bi;
    out[256 + (size_t)b * T_ + (T_ - 1)] = (float)bi;
  }
}

// ============ K5: backtrace — 8-deep double-buffered prefetch ============
__global__ __launch_bounds__(64) void k5_backtrace(
    const u8* __restrict__ bp,
    const int* __restrict__ last,
    float* __restrict__ out)
{
  int b = blockIdx.x * 64 + threadIdx.x;
  const u8* base = bp + (size_t)b * T_ * 32;
  int tag = last[b];
  float* ob = out + 256 + (size_t)b * T_;
  uint4 A0[8], A1[8];
  u32 B0[8], B1[8];
#pragma unroll
  for (int q = 0; q < 8; ++q) {
    const u8* p = base + (size_t)(510 - q) * 32;
    A0[q] = *reinterpret_cast<const uint4*>(p);
    B0[q] = *reinterpret_cast<const u32*>(p + 16);
  }
  int t0 = 510;
  for (int pair = 0; pair < 32; ++pair) {
#pragma unroll
    for (int q = 0; q < 8; ++q) {
      int tn = t0 - 8 - q;
      if (tn >= 0) {
        const u8* p = base + (size_t)tn * 32;
        A1[q] = *reinterpret_cast<const uint4*>(p);
        B1[q] = *reinterpret_cast<const u32*>(p + 16);
      }
    }
#pragma unroll
    for (int q = 0; q < 8; ++q) {
      int t = t0 - q;
      if (t >= 0) {
        uint4 Av = A0[q]; u32 Bw = B0[q];
        u32 dw = (tag < 8) ? ((tag < 4) ? Av.x : Av.y) : ((tag < 12) ? Av.z : Av.w);
        dw = (tag < 16) ? dw : Bw;
        tag = (int)((dw >> ((tag & 3) * 8)) & 0xffu);
        ob[t] = (float)tag;
      }
    }
#pragma unroll
    for (int q = 0; q < 8; ++q) {
      int tn = t0 - 16 - q;
      if (tn >= 0) {
        const u8* p = base + (size_t)tn * 32;
        A0[q] = *reinterpret_cast<const uint4*>(p);
        B0[q] = *reinterpret_cast<const u32*>(p + 16);
      }
    }
#pragma unroll
    for (int q = 0; q < 8; ++q) {
      int t = t0 - 8 - q;
      if (t >= 0) {
        uint4 Av = A1[q]; u32 Bw = B1[q];
        u32 dw = (tag < 8) ? ((tag < 4) ? Av.x : Av.y) : ((tag < 12) ? Av.z : Av.w);
        dw = (tag < 16) ? dw : Bw;
        tag = (int)((dw >> ((tag & 3) * 8)) & 0xffu);
        ob[t] = (float)tag;
      }
    }
    t0 -= 16;
  }
}

extern "C" void kernel_launch(void* const* d_in, const int* in_sizes, int n_in,
                              void* d_out, int out_size, void* d_ws, size_t ws_size,
                              hipStream_t stream) {
  const int*   data  = (const int*)d_in[0];
  const float* emb   = (const float*)d_in[2];
  const float* Wih_f = (const float*)d_in[3];
  const float* Whh_f = (const float*)d_in[4];
  const float* bih_f = (const float*)d_in[5];
  const float* bhh_f = (const float*)d_in[6];
  const float* Wih_b = (const float*)d_in[7];
  const float* Whh_b = (const float*)d_in[8];
  const float* bih_b = (const float*)d_in[9];
  const float* bhh_b = (const float*)d_in[10];
  const float* W_out = (const float*)d_in[11];
  const float* b_out = (const float*)d_in[12];
  const float* trans = (const float*)d_in[13];
  const float* start_trans = (const float*)d_in[14];
  const float* end_trans   = (const float*)d_in[15];

  char* ws = (char*)d_ws;
  float* G    = (float*)(ws + WS_G);
  float* hbuf = (float*)(ws + WS_H);
  float* emit = (float*)(ws + WS_EMIT);
  u8*    bp   = (u8*)(ws + WS_BP);
  int*   lastp = (int*)(ws + WS_LAST);
  float* out = (float*)d_out;

  k1_build_G<<<dim3(250, 2), 256, 0, stream>>>(emb, Wih_f, bih_f, bhh_f,
                                               Wih_b, bih_b, bhh_b, G);
  k2_lstm<<<512, 512, 0, stream>>>(data, G, Whh_f, Whh_b, hbuf);
  k3_emit<<<2048, 256, 0, stream>>>(hbuf, W_out, b_out, emit);
  k4_viterbi<<<256, 64, 0, stream>>>(emit, trans, start_trans, end_trans,
                                     bp, lastp, out);
  k5_backtrace<<<4, 64, 0, stream>>>(bp, lastp, out);
}

// Round 5
// 661.430 us; speedup vs baseline: 1.1867x; 1.0832x over previous
//
#include <hip/hip_runtime.h>
#include <hip/hip_bf16.h>

typedef unsigned int u32;
typedef unsigned char u8;

#define B_ 256
#define T_ 512
#define E_ 100
#define H_ 64
#define K_ 17
#define V_ 8000

// ---- ws layout (bytes) ----
#define WS_G     0            // 2 * 8000 * 256 * 4 = 16,384,000
#define WS_H     16384000     // 2 * 256 * 512 * 64 * 4 = 67,108,864
#define WS_EMIT  83492864     // 131072 * 17 * 4 = 8,912,896
#define WS_BP    92405760     // 256 * 512 * 32 = 4,194,304
#define WS_LAST  96600064     // 256 * 4

// quad_perm DPP: xor1 = [1,0,3,2] = 0xB1, xor2 = [2,3,0,1] = 0x4E
__device__ __forceinline__ float qp_xor1(float v) {
  int r = __builtin_amdgcn_update_dpp(0, __builtin_bit_cast(int, v), 0xB1, 0xF, 0xF, true);
  return __builtin_bit_cast(float, r);
}
__device__ __forceinline__ float qp_xor2(float v) {
  int r = __builtin_amdgcn_update_dpp(0, __builtin_bit_cast(int, v), 0x4E, 0xF, 0xF, true);
  return __builtin_bit_cast(float, r);
}

// ============ K1: G[v][u*4+g] = emb[v] @ Wih[g*64+u].T + bih + bhh ============
__global__ __launch_bounds__(256) void k1_build_G(
    const float* __restrict__ emb,
    const float* __restrict__ Wih_f,
    const float* __restrict__ bih_f,
    const float* __restrict__ bhh_f,
    const float* __restrict__ Wih_b,
    const float* __restrict__ bih_b,
    const float* __restrict__ bhh_b,
    float* __restrict__ G)
{
  __shared__ float xl[32 * E_];
  int v0 = blockIdx.x * 32;
  int dir = blockIdx.y;
  int tid = threadIdx.x;
  const float* Wih = dir ? Wih_b : Wih_f;
  const float* bih = dir ? bih_b : bih_f;
  const float* bhh = dir ? bhh_b : bhh_f;

  for (int i = tid; i < 32 * E_; i += 256) xl[i] = emb[v0 * E_ + i];

  int u = tid >> 2, g = tid & 3;
  int row = (g << 6) + u;
  float4 A4[25];
  {
    const float4* wp = reinterpret_cast<const float4*>(Wih + row * E_); // 400B rows, 16B aligned
#pragma unroll
    for (int q = 0; q < 25; ++q) A4[q] = wp[q];
  }
  float bias = __fadd_rn(bih[row], bhh[row]);
  __syncthreads();

  float* Gd = G + (size_t)dir * V_ * 256;
  for (int vi = 0; vi < 32; ++vi) {
    const float* xp = &xl[vi * E_];   // vi*400B, 16B aligned
    float a0 = bias, a1 = 0.f, a2 = 0.f, a3 = 0.f;
#pragma unroll
    for (int q = 0; q < 25; ++q) {
      float4 w4 = A4[q];
      float4 x4 = *reinterpret_cast<const float4*>(&xp[4 * q]);
      a0 = fmaf(w4.x, x4.x, a0);
      a1 = fmaf(w4.y, x4.y, a1);
      a2 = fmaf(w4.z, x4.z, a2);
      a3 = fmaf(w4.w, x4.w, a3);
    }
    Gd[(v0 + vi) * 256 + tid] = (a0 + a1) + (a2 + a3);
  }
}

// ============ K2: BiLSTM recurrence. 1 block = (b, dir), 4 waves ============
// lane l: unit u = w*16 + (l>>2), K-quarter kq = l&3. All 4 gates per lane.
// h broadcast: 4 ds_read_b128/wave (minimum); combine via DPP quad_perm xor1/xor2.
// Raw s_barrier (lgkmcnt-only drain) keeps G prefetch loads in flight.
__global__ __launch_bounds__(256, 2) void k2_lstm(
    const int* __restrict__ data,
    const float* __restrict__ G,
    const float* __restrict__ Whh_f,
    const float* __restrict__ Whh_b,
    float* __restrict__ hout)
{
  __shared__ __align__(16) float hls[2][64];
  int bid = blockIdx.x;
  int b = bid & 255;
  int dir = bid >> 8;
  int tid = threadIdx.x;
  int w = tid >> 6, l = tid & 63;
  int ul = l >> 2;           // 0..15
  int kq = l & 3;            // K-quarter
  int u = (w << 4) + ul;     // 0..63
  const float* Whh = dir ? Whh_b : Whh_f;

  // W[g][16]: gate g's row, K-slice [kq*16, kq*16+16)
  float W[4][16];
#pragma unroll
  for (int g = 0; g < 4; ++g) {
    const float4* wp = reinterpret_cast<const float4*>(Whh + ((g << 6) + u) * 64 + (kq << 4));
#pragma unroll
    for (int q = 0; q < 4; ++q) {
      float4 v = wp[q];
      W[g][q * 4 + 0] = v.x;
      W[g][q * 4 + 1] = v.y;
      W[g][q * 4 + 2] = v.z;
      W[g][q * 4 + 3] = v.w;
    }
  }
  if (tid < 64) hls[0][tid] = 0.0f;
  float c = 0.0f;
  const int* tokp = data + b * T_;
  const float* Gd = G + (size_t)dir * V_ * 256;
  float* hob = hout + ((size_t)(dir * B_ + b)) * T_ * H_;
  const float L2E = 1.4426950408889634f;

  float4 gq0 = *reinterpret_cast<const float4*>(&Gd[(size_t)tokp[dir ? (T_ - 1) : 0] * 256 + (u << 2)]);
  float4 gq1 = *reinterpret_cast<const float4*>(&Gd[(size_t)tokp[dir ? (T_ - 2) : 1] * 256 + (u << 2)]);
  __syncthreads();

  int cur = 0;
  for (int s = 0; s < T_; ++s) {
    int tt = dir ? (T_ - 1 - s) : s;
    float4 gq2 = make_float4(0.f, 0.f, 0.f, 0.f);
    if (s < T_ - 2) {
      int ttn = dir ? (T_ - 3 - s) : (s + 2);
      gq2 = *reinterpret_cast<const float4*>(&Gd[(size_t)tokp[ttn] * 256 + (u << 2)]);
    }
    const float* hq = hls[cur] + (kq << 4);
    float4 h4[4];
#pragma unroll
    for (int q = 0; q < 4; ++q) h4[q] = *reinterpret_cast<const float4*>(&hq[q * 4]);
    float acc[4];
#pragma unroll
    for (int g = 0; g < 4; ++g) {
      float b0 = 0.f, b1 = 0.f, b2 = 0.f, b3 = 0.f;
#pragma unroll
      for (int q = 0; q < 4; ++q) {
        b0 = fmaf(W[g][q * 4 + 0], h4[q].x, b0);
        b1 = fmaf(W[g][q * 4 + 1], h4[q].y, b1);
        b2 = fmaf(W[g][q * 4 + 2], h4[q].z, b2);
        b3 = fmaf(W[g][q * 4 + 3], h4[q].w, b3);
      }
      acc[g] = (b0 + b1) + (b2 + b3);
    }
    // quad butterfly (DPP, no DS ops): every lane gets full 64-sum for each gate
    float t0 = acc[0] + qp_xor1(acc[0]); float f0 = t0 + qp_xor2(t0);
    float t1 = acc[1] + qp_xor1(acc[1]); float f1 = t1 + qp_xor2(t1);
    float t2 = acc[2] + qp_xor1(acc[2]); float f2 = t2 + qp_xor2(t2);
    float t3 = acc[3] + qp_xor1(acc[3]); float f3 = t3 + qp_xor2(t3);
    float xi = f0 + gq0.x;
    float xf = f1 + gq0.y;
    float xg = f2 + gq0.z;
    float xo = f3 + gq0.w;
    // same activation formulas as round 4 (verified absmax 0.0)
    float si = __builtin_amdgcn_rcpf(1.0f + __builtin_amdgcn_exp2f(xi * (-L2E)));
    float sf = __builtin_amdgcn_rcpf(1.0f + __builtin_amdgcn_exp2f(xf * (-L2E)));
    float tg = fmaf(2.0f, __builtin_amdgcn_rcpf(1.0f + __builtin_amdgcn_exp2f(xg * (-2.0f * L2E))), -1.0f);
    float so = __builtin_amdgcn_rcpf(1.0f + __builtin_amdgcn_exp2f(xo * (-L2E)));
    c = __fadd_rn(__fmul_rn(sf, c), __fmul_rn(si, tg));
    float tc = fmaf(2.0f, __builtin_amdgcn_rcpf(1.0f + __builtin_amdgcn_exp2f(c * (-2.0f * L2E))), -1.0f);
    float hn = __fmul_rn(so, tc);
    if (kq == 0) {
      hls[cur ^ 1][u] = hn;
      hob[tt * H_ + u] = hn;
    }
    // raw barrier: drain LDS only; global prefetch loads stay in flight
    asm volatile("s_waitcnt lgkmcnt(0)\n\ts_barrier" ::: "memory");
    cur ^= 1;
    gq0 = gq1; gq1 = gq2;
  }
}

// ============ K3: emissions = [hf|hb] @ W_out.T + b_out ============
__global__ __launch_bounds__(256) void k3_emit(
    const float* __restrict__ hbuf,
    const float* __restrict__ W_out,
    const float* __restrict__ b_out,
    float* __restrict__ emit)
{
  __shared__ float hl[64][132];
  __shared__ float Wl[17][132];
  int tid = threadIdx.x;
  int p0 = blockIdx.x * 64;  // flat position base (b*T + t), 64 consecutive t
  const float* hf = hbuf;
  const float* hb = hbuf + (size_t)B_ * T_ * H_;
#pragma unroll
  for (int i = 0; i < 4; ++i) {
    int idx = tid + i * 256;       // float4 index among 1024
    int pos = idx >> 4, e4 = idx & 15;
    float4 v = reinterpret_cast<const float4*>(hf + (size_t)p0 * 64)[idx];
    *reinterpret_cast<float4*>(&hl[pos][e4 * 4]) = v;
    float4 v2 = reinterpret_cast<const float4*>(hb + (size_t)p0 * 64)[idx];
    *reinterpret_cast<float4*>(&hl[pos][64 + e4 * 4]) = v2;
  }
  for (int i = tid; i < 17 * 128; i += 256) {
    int k = i >> 7, e = i & 127;
    Wl[k][e] = W_out[i];
  }
  __syncthreads();

  int pos = tid >> 2, ks = tid & 3;
  float acc[5] = {0.f, 0.f, 0.f, 0.f, 0.f};
#pragma unroll
  for (int e4 = 0; e4 < 32; ++e4) {
    float4 x4 = *reinterpret_cast<const float4*>(&hl[pos][e4 * 4]);
#pragma unroll
    for (int kk = 0; kk < 5; ++kk) {
      int k = ks + kk * 4;
      if (k < K_) {
        float4 w4 = *reinterpret_cast<const float4*>(&Wl[k][e4 * 4]);
        acc[kk] = fmaf(x4.x, w4.x, acc[kk]);
        acc[kk] = fmaf(x4.y, w4.y, acc[kk]);
        acc[kk] = fmaf(x4.z, w4.z, acc[kk]);
        acc[kk] = fmaf(x4.w, w4.w, acc[kk]);
      }
    }
  }
#pragma unroll
  for (int kk = 0; kk < 5; ++kk) {
    int k = ks + kk * 4;
    if (k < K_)
      emit[(size_t)(p0 + pos) * K_ + k] = __fadd_rn(acc[kk], b_out[k]);
  }
}

// ============ K4: Viterbi forward. 1 wave per b; lane = (half ic, tag j) ============
#define AMAX(vA, iA, vB, iB) { bool tk_ = (vB) > (vA); if (tk_) { vA = (vB); iA = (iB); } }

__global__ __launch_bounds__(64) void k4_viterbi(
    const float* __restrict__ emit,
    const float* __restrict__ trans,
    const float* __restrict__ start_trans,
    const float* __restrict__ end_trans,
    u8* __restrict__ bp,
    int* __restrict__ last,
    float* __restrict__ out)
{
  int b = blockIdx.x;
  int l = threadIdx.x;
  int ic = l >> 5;
  int hbase = l & 32;
  int j = l & 31;
  int jc = (j < K_) ? j : 0;
  int i0 = ic ? 9 : 0;
  int cnt = ic ? 8 : 9;
  float tr[9];
#pragma unroll
  for (int q = 0; q < 9; ++q)
    tr[q] = (q < cnt) ? trans[(i0 + q) * K_ + jc] : -__builtin_inff();
  const float* eb = emit + (size_t)b * T_ * K_;
  float endt = end_trans[jc];
  float s = __fadd_rn(start_trans[jc], eb[jc]);
  u8* bpb = bp + (size_t)b * T_ * 32;
  // 4-deep emission prefetch ring
  float er0 = eb[1 * K_ + jc];
  float er1 = eb[2 * K_ + jc];
  float er2 = eb[3 * K_ + jc];
  float er3 = eb[4 * K_ + jc];

  for (int t = 1; t < T_; ++t) {
    float ej = er0;
    er0 = er1; er1 = er2; er2 = er3;
    if (t + 4 < T_) er3 = eb[(size_t)(t + 4) * K_ + jc];
    float sv[9];
#pragma unroll
    for (int q = 0; q < 9; ++q) sv[q] = __shfl(s, hbase + i0 + q, 64);
    // np rounding order: cand = (score_i + trans_ij) + emit_j
    float cd[9];
#pragma unroll
    for (int q = 0; q < 9; ++q) cd[q] = __fadd_rn(__fadd_rn(sv[q], tr[q]), ej);
    // tree argmax; strict > with left-priority == np first-index tie rule
    float v01 = cd[0]; int x01 = i0;     AMAX(v01, x01, cd[1], i0 + 1);
    float v23 = cd[2]; int x23 = i0 + 2; AMAX(v23, x23, cd[3], i0 + 3);
    float v45 = cd[4]; int x45 = i0 + 4; AMAX(v45, x45, cd[5], i0 + 5);
    float v67 = cd[6]; int x67 = i0 + 6; AMAX(v67, x67, cd[7], i0 + 7);
    AMAX(v01, x01, v23, x23);
    AMAX(v45, x45, v67, x67);
    AMAX(v01, x01, v45, x45);
    AMAX(v01, x01, cd[8], i0 + 8);
    float m = v01; int idx = x01;
    float m2 = __shfl_xor(m, 32, 64);
    int idx2 = __shfl_xor(idx, 32, 64);
    bool take = (m2 > m) || ((m2 == m) && (idx2 < idx));
    if (take) { m = m2; idx = idx2; }
    s = m;
    if (ic == 0 && j < K_) bpb[(size_t)(t - 1) * 32 + j] = (u8)idx;
  }
  float fin = __fadd_rn(s, endt);
  float bm = __shfl(fin, hbase, 64);
  int bi = 0;
#pragma unroll
  for (int jj = 1; jj < K_; ++jj) {
    float v = __shfl(fin, hbase + jj, 64);
    if (v > bm) { bm = v; bi = jj; }
  }
  if (l == 0) {
    out[b] = bm;
    last[b] = bi;
    out[256 + (size_t)b * T_ + (T_ - 1)] = (float)bi;
  }
}

// ============ K5: backtrace — 8-deep double-buffered prefetch ============
__global__ __launch_bounds__(64) void k5_backtrace(
    const u8* __restrict__ bp,
    const int* __restrict__ last,
    float* __restrict__ out)
{
  int b = blockIdx.x * 64 + threadIdx.x;
  const u8* base = bp + (size_t)b * T_ * 32;
  int tag = last[b];
  float* ob = out + 256 + (size_t)b * T_;
  uint4 A0[8], A1[8];
  u32 B0[8], B1[8];
#pragma unroll
  for (int q = 0; q < 8; ++q) {
    const u8* p = base + (size_t)(510 - q) * 32;
    A0[q] = *reinterpret_cast<const uint4*>(p);
    B0[q] = *reinterpret_cast<const u32*>(p + 16);
  }
  int t0 = 510;
  for (int pair = 0; pair < 32; ++pair) {
#pragma unroll
    for (int q = 0; q < 8; ++q) {
      int tn = t0 - 8 - q;
      if (tn >= 0) {
        const u8* p = base + (size_t)tn * 32;
        A1[q] = *reinterpret_cast<const uint4*>(p);
        B1[q] = *reinterpret_cast<const u32*>(p + 16);
      }
    }
#pragma unroll
    for (int q = 0; q < 8; ++q) {
      int t = t0 - q;
      if (t >= 0) {
        uint4 Av = A0[q]; u32 Bw = B0[q];
        u32 dw = (tag < 8) ? ((tag < 4) ? Av.x : Av.y) : ((tag < 12) ? Av.z : Av.w);
        dw = (tag < 16) ? dw : Bw;
        tag = (int)((dw >> ((tag & 3) * 8)) & 0xffu);
        ob[t] = (float)tag;
      }
    }
#pragma unroll
    for (int q = 0; q < 8; ++q) {
      int tn = t0 - 16 - q;
      if (tn >= 0) {
        const u8* p = base + (size_t)tn * 32;
        A0[q] = *reinterpret_cast<const uint4*>(p);
        B0[q] = *reinterpret_cast<const u32*>(p + 16);
      }
    }
#pragma unroll
    for (int q = 0; q < 8; ++q) {
      int t = t0 - 8 - q;
      if (t >= 0) {
        uint4 Av = A1[q]; u32 Bw = B1[q];
        u32 dw = (tag < 8) ? ((tag < 4) ? Av.x : Av.y) : ((tag < 12) ? Av.z : Av.w);
        dw = (tag < 16) ? dw : Bw;
        tag = (int)((dw >> ((tag & 3) * 8)) & 0xffu);
        ob[t] = (float)tag;
      }
    }
    t0 -= 16;
  }
}

extern "C" void kernel_launch(void* const* d_in, const int* in_sizes, int n_in,
                              void* d_out, int out_size, void* d_ws, size_t ws_size,
                              hipStream_t stream) {
  const int*   data  = (const int*)d_in[0];
  const float* emb   = (const float*)d_in[2];
  const float* Wih_f = (const float*)d_in[3];
  const float* Whh_f = (const float*)d_in[4];
  const float* bih_f = (const float*)d_in[5];
  const float* bhh_f = (const float*)d_in[6];
  const float* Wih_b = (const float*)d_in[7];
  const float* Whh_b = (const float*)d_in[8];
  const float* bih_b = (const float*)d_in[9];
  const float* bhh_b = (const float*)d_in[10];
  const float* W_out = (const float*)d_in[11];
  const float* b_out = (const float*)d_in[12];
  const float* trans = (const float*)d_in[13];
  const float* start_trans = (const float*)d_in[14];
  const float* end_trans   = (const float*)d_in[15];

  char* ws = (char*)d_ws;
  float* G    = (float*)(ws + WS_G);
  float* hbuf = (float*)(ws + WS_H);
  float* emit = (float*)(ws + WS_EMIT);
  u8*    bp   = (u8*)(ws + WS_BP);
  int*   lastp = (int*)(ws + WS_LAST);
  float* out = (float*)d_out;

  k1_build_G<<<dim3(250, 2), 256, 0, stream>>>(emb, Wih_f, bih_f, bhh_f,
                                               Wih_b, bih_b, bhh_b, G);
  k2_lstm<<<512, 256, 0, stream>>>(data, G, Whh_f, Whh_b, hbuf);
  k3_emit<<<2048, 256, 0, stream>>>(hbuf, W_out, b_out, emit);
  k4_viterbi<<<256, 64, 0, stream>>>(emit, trans, start_trans, end_trans,
                                     bp, lastp, out);
  k5_backtrace<<<4, 64, 0, stream>>>(bp, lastp, out);
}